// Round 1
// baseline (454.187 us; speedup 1.0000x reference)
//
#include <hip/hip_runtime.h>
#include <cstdint>
#include <cstddef>

// ---------------------------------------------------------------------------
// Adaptive log-softmax NLL (TransformerXL ProjectedAdaptiveLogSoftmax style)
// hidden[1024,1024] f32; vocab clusters: [0,20000,60000,180000,267735]
// Strategy: bf16 MFMA GEMMs fused with online logsumexp (never materialize
// full logits). W matrices are transposed+converted to bf16 [N][K] in ws
// (one reusable buffer), then a 256x128x64 MFMA GEMM produces per-(row,tile)
// (max, sumexp) partials; small kernels do target logits and the final
// combine. Accuracy budget: threshold 0.53 abs; bf16 path error ~1e-2.
// ---------------------------------------------------------------------------

typedef unsigned short u16;
typedef __attribute__((ext_vector_type(8))) __bf16 bf16x8;
typedef __attribute__((ext_vector_type(8))) u16 u16x8;
typedef __attribute__((ext_vector_type(4))) float f32x4;

#define AS1 __attribute__((address_space(1)))
#define AS3 __attribute__((address_space(3)))

struct MS { float m, s; };

__device__ __forceinline__ u16 f2bf(float f){
  union { float f; unsigned u; } v; v.f = f;
  unsigned r = v.u + 0x7fffu + ((v.u >> 16) & 1u);  // RNE
  return (u16)(r >> 16);
}
__device__ __forceinline__ float bf2f(u16 x){
  union { unsigned u; float f; } v; v.u = ((unsigned)x) << 16;
  return v.f;
}
// async global->LDS, 16B per lane. LDS dest is wave-uniform base + lane*16.
__device__ __forceinline__ void glds16(const void* g, void* l){
  __builtin_amdgcn_global_load_lds((AS1 unsigned*)(uintptr_t)g,
                                   (AS3 unsigned*)(unsigned)(uintptr_t)l, 16, 0, 0);
}

// ---------------- hidden f32 -> bf16 ----------------
__global__ void k_cvt_hidden(const float* __restrict__ h, u16* __restrict__ a0){
  int i = (blockIdx.x * 256 + threadIdx.x) * 8;   // 1M elements total
  f32x4 v0 = *(const f32x4*)(h + i);
  f32x4 v1 = *(const f32x4*)(h + i + 4);
  u16x8 o;
  o[0]=f2bf(v0.x); o[1]=f2bf(v0.y); o[2]=f2bf(v0.z); o[3]=f2bf(v0.w);
  o[4]=f2bf(v1.x); o[5]=f2bf(v1.y); o[6]=f2bf(v1.z); o[7]=f2bf(v1.w);
  *(u16x8*)(a0 + i) = o;
}

// ---------------- projections (fp32) + cluster logits ----------------
// 256 blocks x 4 rows. hidden reads are wave-uniform -> scalar loads.
__global__ void k_proj(const float* __restrict__ hidden,
                       const float* __restrict__ Wp1, const float* __restrict__ Wp2,
                       const float* __restrict__ Wp3, const float* __restrict__ Wc,
                       const float* __restrict__ bc,
                       u16* __restrict__ A1, u16* __restrict__ A2,
                       u16* __restrict__ A3, float* __restrict__ cl)
{
  const int r0 = blockIdx.x * 4;
  const int c = threadIdx.x;
  const float* W = nullptr; int cc = 0, str = 0;
  if (c < 256)      { W = Wp1; cc = c;       str = 256; }
  else if (c < 320) { W = Wp2; cc = c - 256; str = 64;  }
  else if (c < 336) { W = Wp3; cc = c - 320; str = 16;  }
  else if (c < 339) { W = Wc;  cc = c - 336; str = 3;   }
  float s0=0.f, s1=0.f, s2=0.f, s3=0.f;
  if (W){
    const float* h0 = hidden + (size_t)r0 * 1024;
    #pragma unroll 4
    for (int k = 0; k < 1024; ++k){
      float w = W[(size_t)k * str + cc];
      s0 += h0[k]        * w;
      s1 += h0[1024 + k] * w;
      s2 += h0[2048 + k] * w;
      s3 += h0[3072 + k] * w;
    }
  }
  float sv[4] = {s0, s1, s2, s3};
  if (c < 256){      for (int r=0;r<4;++r) A1[(size_t)(r0+r)*256 + cc] = f2bf(sv[r]); }
  else if (c < 320){ for (int r=0;r<4;++r) A2[(size_t)(r0+r)*64  + cc] = f2bf(sv[r]); }
  else if (c < 336){ for (int r=0;r<4;++r) A3[(size_t)(r0+r)*32  + cc] = f2bf(sv[r]); }
  else if (c < 339){ for (int r=0;r<4;++r) cl[(size_t)(r0+r)*3   + cc] = sv[r] + bc[cc]; }
  else if (c < 355){ int pc = 16 + (c - 339);   // zero-pad proj3 K 16->32
                     for (int r=0;r<4;++r) A3[(size_t)(r0+r)*32 + pc] = 0; }
}

// ---------------- W [K][N] f32 -> BT [Npad][Kpad] bf16 (transposed) --------
__global__ void k_transpose(const float* __restrict__ W, int K, int N,
                            u16* __restrict__ BT, int Kpad)
{
  __shared__ float t[64][65];
  const int n0 = blockIdx.x * 64;
  const int k0 = blockIdx.y * 64;
  const bool al = (N & 3) == 0;  // f32x4-alignment of row starts
  for (int i = threadIdx.x; i < 64*16; i += 256){
    int r = i >> 4, c4 = (i & 15) * 4;
    int k = k0 + r, n = n0 + c4;
    f32x4 v; v.x=0.f; v.y=0.f; v.z=0.f; v.w=0.f;
    if (k < K){
      if (al && n + 3 < N) v = *(const f32x4*)(W + (size_t)k * N + n);
      else { for (int j = 0; j < 4; ++j) if (n + j < N) v[j] = W[(size_t)k * N + n + j]; }
    }
    t[r][c4] = v.x; t[r][c4+1] = v.y; t[r][c4+2] = v.z; t[r][c4+3] = v.w;
  }
  __syncthreads();
  for (int i = threadIdx.x; i < 64*8; i += 256){
    int rn = i >> 3, c8 = (i & 7) * 8;
    if (k0 + c8 < Kpad){
      u16x8 o;
      #pragma unroll
      for (int j = 0; j < 8; ++j) o[j] = f2bf(t[c8 + j][rn]);
      *(u16x8*)(BT + (size_t)(n0 + rn) * Kpad + k0 + c8) = o;
    }
  }
}

// ---------------- fused GEMM + partial logsumexp ----------------
// A [1024][K] bf16, BT [Npad][K] bf16, bias [N] f32.
// BM=256 BN=128, 8 waves (4 row-groups x 2 col-groups), 16x16x32 bf16 MFMA.
// Epilogue: per-row (max, sum exp) over the 128-col tile -> P[row][tile].
template<int BK>
__global__ __launch_bounds__(512)
void k_gemm_lse(const u16* __restrict__ A, const u16* __restrict__ BT,
                const float* __restrict__ bias, int K, int N,
                MS* __restrict__ P, int ntiles)
{
  constexpr int BM = 256, BN = 128;
  __shared__ u16 As[BM * BK];
  __shared__ u16 Bs[BN * BK];
  __shared__ float redm[2][256];
  __shared__ float reds[2][256];

  const int tid  = threadIdx.x;
  const int lane = tid & 63, wid = tid >> 6;
  const int wm = wid & 3, wn = wid >> 2;
  const int l15 = lane & 15, l4 = lane >> 4;
  const int m0 = blockIdx.y * BM;
  const int n0 = blockIdx.x * BN;

  f32x4 acc[4][4];
  #pragma unroll
  for (int m = 0; m < 4; ++m)
    #pragma unroll
    for (int n = 0; n < 4; ++n){ acc[m][n].x=0.f; acc[m][n].y=0.f; acc[m][n].z=0.f; acc[m][n].w=0.f; }

  constexpr int LPR  = BK / 8;        // lanes (16B units) per LDS row
  constexpr int RPC  = 64 / LPR;      // rows per 1KB chunk
  constexpr int ACPW = BM / RPC / 8;  // A chunks per wave
  constexpr int BCPW = BN / RPC / 8;  // B chunks per wave

  const int ksteps = K / BK;
  for (int kt = 0; kt < ksteps; ++kt){
    #pragma unroll
    for (int i = 0; i < ACPW; ++i){
      int c = wid * ACPW + i;
      int row = c * RPC + lane / LPR;
      int kb  = lane % LPR;
      glds16((const char*)(A + (size_t)(m0 + row) * K + kt * BK) + kb * 16,
             (char*)As + c * 1024);
    }
    #pragma unroll
    for (int i = 0; i < BCPW; ++i){
      int c = wid * BCPW + i;
      int row = c * RPC + lane / LPR;
      int kb  = lane % LPR;
      glds16((const char*)(BT + (size_t)(n0 + row) * K + kt * BK) + kb * 16,
             (char*)Bs + c * 1024);
    }
    __syncthreads();
    #pragma unroll
    for (int ks = 0; ks < BK / 32; ++ks){
      bf16x8 af[4], bfr[4];
      #pragma unroll
      for (int m = 0; m < 4; ++m)
        af[m] = *(const bf16x8*)((const char*)As + (wm*64 + m*16 + l15) * (BK*2) + ks*64 + l4*16);
      #pragma unroll
      for (int n = 0; n < 4; ++n)
        bfr[n] = *(const bf16x8*)((const char*)Bs + (wn*64 + n*16 + l15) * (BK*2) + ks*64 + l4*16);
      #pragma unroll
      for (int m = 0; m < 4; ++m)
        #pragma unroll
        for (int n = 0; n < 4; ++n)
          acc[m][n] = __builtin_amdgcn_mfma_f32_16x16x32_bf16(af[m], bfr[n], acc[m][n], 0, 0, 0);
    }
    __syncthreads();
  }

  // ---- epilogue: per-row max / sumexp over this 128-col tile ----
  float bv[4]; bool val[4];
  #pragma unroll
  for (int n = 0; n < 4; ++n){
    int col = n0 + wn*64 + n*16 + l15;
    val[n] = col < N;
    bv[n] = val[n] ? bias[col] : 0.f;
  }
  #pragma unroll
  for (int m = 0; m < 4; ++m)
    #pragma unroll
    for (int q = 0; q < 4; ++q){
      float mx = -1e30f;
      #pragma unroll
      for (int n = 0; n < 4; ++n)
        if (val[n]) mx = fmaxf(mx, acc[m][n][q] + bv[n]);
      #pragma unroll
      for (int d = 1; d < 16; d <<= 1) mx = fmaxf(mx, __shfl_xor(mx, d));
      if (l15 == 0) redm[wn][wm*64 + m*16 + l4*4 + q] = mx;
    }
  __syncthreads();
  #pragma unroll
  for (int m = 0; m < 4; ++m)
    #pragma unroll
    for (int q = 0; q < 4; ++q){
      int lrow = wm*64 + m*16 + l4*4 + q;
      float M = fmaxf(redm[0][lrow], redm[1][lrow]);
      float s = 0.f;
      #pragma unroll
      for (int n = 0; n < 4; ++n)
        if (val[n]) s += __expf(acc[m][n][q] + bv[n] - M);
      #pragma unroll
      for (int d = 1; d < 16; d <<= 1) s += __shfl_xor(s, d);
      if (l15 == 0) reds[wn][lrow] = s;
    }
  __syncthreads();
  if (wn == 0 && l15 == 0){
    #pragma unroll
    for (int m = 0; m < 4; ++m)
      #pragma unroll
      for (int q = 0; q < 4; ++q){
        int lrow = wm*64 + m*16 + l4*4 + q;
        MS r; r.m = fmaxf(redm[0][lrow], redm[1][lrow]);
        r.s = reds[0][lrow] + reds[1][lrow];
        P[(size_t)(m0 + lrow) * ntiles + blockIdx.x] = r;
      }
  }
}

// ---------------- target logit for tokens in [start,end) ----------------
__global__ void k_target(const int* __restrict__ tgt, const u16* __restrict__ A,
                         const u16* __restrict__ BT, const float* __restrict__ bias,
                         int start, int end, int K, float* __restrict__ tl)
{
  int n = blockIdx.x * 4 + (threadIdx.x >> 6);
  int lane = threadIdx.x & 63;
  int t = tgt[n];
  if (t < start || t >= end) return;
  int rel = t - start;
  const u16* a = A  + (size_t)n   * K;
  const u16* b = BT + (size_t)rel * K;
  float s = 0.f;
  for (int k = lane * 8; k < K; k += 512){
    u16x8 av = *(const u16x8*)(a + k);
    u16x8 bv = *(const u16x8*)(b + k);
    #pragma unroll
    for (int j = 0; j < 8; ++j) s += bf2f(av[j]) * bf2f(bv[j]);
  }
  #pragma unroll
  for (int d = 1; d < 64; d <<= 1) s += __shfl_xor(s, d);
  if (lane == 0) tl[n] = s + bias[rel];
}

// ---------------- final combine ----------------
__device__ __forceinline__ void lse_merge(float& m, float& s, float m2, float s2){
  float M = fmaxf(m, m2);
  s = s * __expf(m - M) + s2 * __expf(m2 - M);
  m = M;
}

__global__ void k_finalize(const int* __restrict__ tgt, const MS* __restrict__ P,
                           const float* __restrict__ cl, const float* __restrict__ tl,
                           float* __restrict__ out)
{
  const int NT0 = 157, NT1 = 313, NT2 = 938, NT3 = 686;
  int n = blockIdx.x * 4 + (threadIdx.x >> 6);
  int lane = threadIdx.x & 63;
  int t = tgt[n];

  // head LSE: partials + 3 cluster logits (concat semantics)
  float m = -1e30f, s = 0.f;
  const MS* p0 = P + (size_t)n * NT0;
  for (int i = lane; i < NT0; i += 64){ MS v = p0[i]; lse_merge(m, s, v.m, v.s); }
  if (lane < 3) lse_merge(m, s, cl[n*3 + lane], 1.f);
  #pragma unroll
  for (int d = 1; d < 64; d <<= 1){
    float m2 = __shfl_xor(m, d), s2 = __shfl_xor(s, d);
    lse_merge(m, s, m2, s2);
  }
  float lse_head = m + logf(s);

  float nll;
  if (t < 20000){
    nll = lse_head - tl[n];
  } else {
    int seg, nt; size_t base;
    if      (t <  60000){ seg = 1; nt = NT1; base = (size_t)1024 * NT0; }
    else if (t < 180000){ seg = 2; nt = NT2; base = (size_t)1024 * (NT0 + NT1); }
    else                { seg = 3; nt = NT3; base = (size_t)1024 * (NT0 + NT1 + NT2); }
    float m2 = -1e30f, s2 = 0.f;
    const MS* ps = P + base + (size_t)n * nt;
    for (int i = lane; i < nt; i += 64){ MS v = ps[i]; lse_merge(m2, s2, v.m, v.s); }
    #pragma unroll
    for (int d = 1; d < 64; d <<= 1){
      float mm = __shfl_xor(m2, d), ss = __shfl_xor(s2, d);
      lse_merge(m2, s2, mm, ss);
    }
    float lse_t = m2 + logf(s2);
    // reference quirk: bucket i uses head_lp[:, -i] == cluster logit index 3-i
    nll = lse_head - cl[n*3 + (3 - seg)] + lse_t - tl[n];
  }
  if (lane == 0) out[n] = nll;
}

// ---------------------------------------------------------------------------
extern "C" void kernel_launch(void* const* d_in, const int* in_sizes, int n_in,
                              void* d_out, int out_size, void* d_ws, size_t ws_size,
                              hipStream_t stream)
{
  const float* hidden = (const float*)d_in[0];
  const int*   target = (const int*)d_in[1];
  const float* W_head = (const float*)d_in[2];
  const float* b_head = (const float*)d_in[3];
  const float* W_clu  = (const float*)d_in[4];
  const float* b_clu  = (const float*)d_in[5];
  const float* W_p1   = (const float*)d_in[6];
  const float* W_t1   = (const float*)d_in[7];
  const float* b_t1   = (const float*)d_in[8];
  const float* W_p2   = (const float*)d_in[9];
  const float* W_t2   = (const float*)d_in[10];
  const float* b_t2   = (const float*)d_in[11];
  const float* W_p3   = (const float*)d_in[12];
  const float* W_t3   = (const float*)d_in[13];
  const float* b_t3   = (const float*)d_in[14];
  float* out = (float*)d_out;

  // workspace layout (bytes, 256-aligned; total 61,149,184 ~ 58.3 MiB)
  char* ws = (char*)d_ws;
  u16*   A0 = (u16*)(ws + 0);          // [1024][1024] bf16
  u16*   A1 = (u16*)(ws + 2097152);    // [1024][256]
  u16*   A2 = (u16*)(ws + 2621440);    // [1024][64]
  u16*   A3 = (u16*)(ws + 2752512);    // [1024][32] (K padded 16->32)
  float* cl = (float*)(ws + 2818048);  // [1024][3]
  float* tl = (float*)(ws + 2834432);  // [1024]
  MS*    P  = (MS*)(ws + 2838528);     // [1024][157+313+938+686]
  u16*   BT = (u16*)(ws + 19992576);   // reusable transposed-W buffer (41.2 MB)

  k_cvt_hidden<<<512, 256, 0, stream>>>(hidden, A0);
  k_proj<<<256, 384, 0, stream>>>(hidden, W_p1, W_p2, W_p3, W_clu, b_clu, A1, A2, A3, cl);

  // seg0: head (K=1024, N=20000, Npad=20096, 157 tiles)
  k_transpose<<<dim3(314, 16), 256, 0, stream>>>(W_head, 1024, 20000, BT, 1024);
  k_gemm_lse<64><<<dim3(157, 4), 512, 0, stream>>>(A0, BT, b_head, 1024, 20000, P, 157);
  k_target<<<256, 256, 0, stream>>>(target, A0, BT, b_head, 0, 20000, 1024, tl);

  // seg1: tail1 (K=256, N=40000, Npad=40064, 313 tiles)
  k_transpose<<<dim3(626, 4), 256, 0, stream>>>(W_t1, 256, 40000, BT, 256);
  k_gemm_lse<64><<<dim3(313, 4), 512, 0, stream>>>(A1, BT, b_t1, 256, 40000, P + (size_t)1024*157, 313);
  k_target<<<256, 256, 0, stream>>>(target, A1, BT, b_t1, 20000, 60000, 256, tl);

  // seg2: tail2 (K=64, N=120000, Npad=120064, 938 tiles)
  k_transpose<<<dim3(1876, 1), 256, 0, stream>>>(W_t2, 64, 120000, BT, 64);
  k_gemm_lse<64><<<dim3(938, 4), 512, 0, stream>>>(A2, BT, b_t2, 64, 120000, P + (size_t)1024*(157+313), 938);
  k_target<<<256, 256, 0, stream>>>(target, A2, BT, b_t2, 60000, 180000, 64, tl);

  // seg3: tail3 (K=16 padded to 32, N=87735, Npad=87808, 686 tiles)
  k_transpose<<<dim3(1372, 1), 256, 0, stream>>>(W_t3, 16, 87735, BT, 32);
  k_gemm_lse<32><<<dim3(686, 4), 512, 0, stream>>>(A3, BT, b_t3, 32, 87735, P + (size_t)1024*(157+313+938), 686);
  k_target<<<256, 256, 0, stream>>>(target, A3, BT, b_t3, 180000, 267735, 32, tl);

  k_finalize<<<256, 256, 0, stream>>>(target, P, cl, tl, out);
}

// Round 2
// 328.147 us; speedup vs baseline: 1.3841x; 1.3841x over previous
//
#include <hip/hip_runtime.h>
#include <cstdint>
#include <cstddef>

// ---------------------------------------------------------------------------
// Adaptive log-softmax NLL. bf16 MFMA GEMMs fused with online logsumexp.
// R2: k_proj (113us latency-bound) -> MFMA proj GEMM; token compaction so
// tail GEMMs only cover rows with in-bucket targets (early-exit row blocks).
// ---------------------------------------------------------------------------

typedef unsigned short u16;
typedef __attribute__((ext_vector_type(8))) __bf16 bf16x8;
typedef __attribute__((ext_vector_type(8))) u16 u16x8;
typedef __attribute__((ext_vector_type(4))) float f32x4;

#define AS1 __attribute__((address_space(1)))
#define AS3 __attribute__((address_space(3)))

struct MS { float m, s; };

__device__ __forceinline__ u16 f2bf(float f){
  union { float f; unsigned u; } v; v.f = f;
  unsigned r = v.u + 0x7fffu + ((v.u >> 16) & 1u);  // RNE
  return (u16)(r >> 16);
}
__device__ __forceinline__ float bf2f(u16 x){
  union { unsigned u; float f; } v; v.u = ((unsigned)x) << 16;
  return v.f;
}
__device__ __forceinline__ void glds16(const void* g, void* l){
  __builtin_amdgcn_global_load_lds((AS1 unsigned*)(uintptr_t)g,
                                   (AS3 unsigned*)(unsigned)(uintptr_t)l, 16, 0, 0);
}

// ---------------- hidden f32 -> bf16 (+ zero bucket counters) ----------------
__global__ void k_cvt_hidden(const float* __restrict__ h, u16* __restrict__ a0,
                             int* __restrict__ cnt){
  if (blockIdx.x == 0 && threadIdx.x < 4) cnt[threadIdx.x] = 0;
  int i = (blockIdx.x * 256 + threadIdx.x) * 8;
  f32x4 v0 = *(const f32x4*)(h + i);
  f32x4 v1 = *(const f32x4*)(h + i + 4);
  u16x8 o;
  o[0]=f2bf(v0.x); o[1]=f2bf(v0.y); o[2]=f2bf(v0.z); o[3]=f2bf(v0.w);
  o[4]=f2bf(v1.x); o[5]=f2bf(v1.y); o[6]=f2bf(v1.z); o[7]=f2bf(v1.w);
  *(u16x8*)(a0 + i) = o;
}

// ---------------- bucket compaction ----------------
// Order within a bucket is atomic-nondeterministic; harmless: per-row GEMM
// values are row-position-independent and results scatter back via pos[n].
__global__ void k_compact(const int* __restrict__ tgt, int* __restrict__ cnt,
                          int* __restrict__ idx1, int* __restrict__ idx2,
                          int* __restrict__ idx3, int* __restrict__ pos){
  int n = blockIdx.x * 256 + threadIdx.x;
  int t = tgt[n];
  int p = 0;
  if (t >= 20000){
    int b = (t < 60000) ? 0 : (t < 180000 ? 1 : 2);
    p = atomicAdd(&cnt[b], 1);
    int* ix = (b == 0) ? idx1 : (b == 1 ? idx2 : idx3);
    ix[p] = n;
  }
  pos[n] = p;
}

// ---------------- gather compacted tail-A rows ----------------
__global__ void k_gather(const int* __restrict__ cnt,
                         const int* __restrict__ idx1, const int* __restrict__ idx2,
                         const int* __restrict__ idx3,
                         const u16* __restrict__ A1, const u16* __restrict__ A2,
                         const u16* __restrict__ A3,
                         u16* __restrict__ A1c, u16* __restrict__ A2c,
                         u16* __restrict__ A3c){
  int u = blockIdx.x * 256 + threadIdx.x;
  const u16* src; u16* dst;
  if (u < 32768){                       // A1: 1024 rows x 32 chunks(16B)
    int r = u >> 5, c = u & 31;
    if (r >= cnt[0]) return;
    src = A1 + (size_t)idx1[r] * 256 + c * 8;
    dst = A1c + (size_t)r * 256 + c * 8;
  } else if (u < 40960){                // A2: 1024 x 8
    int v = u - 32768; int r = v >> 3, c = v & 7;
    if (r >= cnt[1]) return;
    src = A2 + (size_t)idx2[r] * 64 + c * 8;
    dst = A2c + (size_t)r * 64 + c * 8;
  } else {                              // A3: 1024 x 4
    int v = u - 40960; int r = v >> 2, c = v & 3;
    if (r >= cnt[2]) return;
    src = A3 + (size_t)idx3[r] * 32 + c * 8;
    dst = A3c + (size_t)r * 32 + c * 8;
  }
  *(u16x8*)dst = *(const u16x8*)src;
}

// ---------------- W [K][N] f32 -> BT [N64][Kpad] bf16 (transposed) --------
__global__ void k_transpose(const float* __restrict__ W, int K, int N,
                            u16* __restrict__ BT, int Kpad)
{
  __shared__ float t[64][65];
  const int n0 = blockIdx.x * 64;
  const int k0 = blockIdx.y * 64;
  const bool al = (N & 3) == 0;
  for (int i = threadIdx.x; i < 64*16; i += 256){
    int r = i >> 4, c4 = (i & 15) * 4;
    int k = k0 + r, n = n0 + c4;
    f32x4 v; v.x=0.f; v.y=0.f; v.z=0.f; v.w=0.f;
    if (k < K){
      if (al && n + 3 < N) v = *(const f32x4*)(W + (size_t)k * N + n);
      else { for (int j = 0; j < 4; ++j) if (n + j < N) v[j] = W[(size_t)k * N + n + j]; }
    }
    t[r][c4] = v.x; t[r][c4+1] = v.y; t[r][c4+2] = v.z; t[r][c4+3] = v.w;
  }
  __syncthreads();
  for (int i = threadIdx.x; i < 64*8; i += 256){
    int rn = i >> 3, c8 = (i & 7) * 8;
    if (k0 + c8 < Kpad){
      u16x8 o;
      #pragma unroll
      for (int j = 0; j < 8; ++j) o[j] = f2bf(t[c8 + j][rn]);
      *(u16x8*)(BT + (size_t)(n0 + rn) * Kpad + k0 + c8) = o;
    }
  }
}

// ---------------- projection GEMM: A0[1024][1024] x BTp[384][1024]^T -------
// cols 0-255 -> A1 bf16, 256-319 -> A2, 320-335 -> A3 (K-pad col+16 zeroed),
// 336-338 -> cl (f32, +b_cluster), 339+ discarded.
__global__ __launch_bounds__(512)
void k_proj_gemm(const u16* __restrict__ A, const u16* __restrict__ BT,
                 const float* __restrict__ bc,
                 u16* __restrict__ A1, u16* __restrict__ A2,
                 u16* __restrict__ A3, float* __restrict__ cl)
{
  constexpr int BK = 64, K = 1024;
  __shared__ u16 As[256 * BK];
  __shared__ u16 Bs[128 * BK];
  const int tid  = threadIdx.x;
  const int lane = tid & 63, wid = tid >> 6;
  const int wm = wid & 3, wn = wid >> 2;
  const int l15 = lane & 15, l4 = lane >> 4;
  const int m0 = blockIdx.y * 256;
  const int n0 = blockIdx.x * 128;

  f32x4 acc[4][4];
  #pragma unroll
  for (int m = 0; m < 4; ++m)
    #pragma unroll
    for (int n = 0; n < 4; ++n){ acc[m][n].x=0.f; acc[m][n].y=0.f; acc[m][n].z=0.f; acc[m][n].w=0.f; }

  for (int kt = 0; kt < K / BK; ++kt){
    #pragma unroll
    for (int i = 0; i < 4; ++i){
      int c = wid * 4 + i;
      int row = c * 8 + lane / 8, kb = lane % 8;
      glds16((const char*)(A + (size_t)(m0 + row) * K + kt * BK) + kb * 16,
             (char*)As + c * 1024);
    }
    #pragma unroll
    for (int i = 0; i < 2; ++i){
      int c = wid * 2 + i;
      int row = c * 8 + lane / 8, kb = lane % 8;
      glds16((const char*)(BT + (size_t)(n0 + row) * K + kt * BK) + kb * 16,
             (char*)Bs + c * 1024);
    }
    __syncthreads();
    #pragma unroll
    for (int ks = 0; ks < 2; ++ks){
      bf16x8 af[4], bfr[4];
      #pragma unroll
      for (int m = 0; m < 4; ++m)
        af[m] = *(const bf16x8*)((const char*)As + (wm*64 + m*16 + l15) * (BK*2) + ks*64 + l4*16);
      #pragma unroll
      for (int n = 0; n < 4; ++n)
        bfr[n] = *(const bf16x8*)((const char*)Bs + (wn*64 + n*16 + l15) * (BK*2) + ks*64 + l4*16);
      #pragma unroll
      for (int m = 0; m < 4; ++m)
        #pragma unroll
        for (int n = 0; n < 4; ++n)
          acc[m][n] = __builtin_amdgcn_mfma_f32_16x16x32_bf16(af[m], bfr[n], acc[m][n], 0, 0, 0);
    }
    __syncthreads();
  }
  #pragma unroll
  for (int m = 0; m < 4; ++m)
    #pragma unroll
    for (int n = 0; n < 4; ++n)
      #pragma unroll
      for (int q = 0; q < 4; ++q){
        int c = n0 + wn*64 + n*16 + l15;
        int r = m0 + wm*64 + m*16 + l4*4 + q;
        float v = acc[m][n][q];
        if (c < 256)      A1[(size_t)r*256 + c] = f2bf(v);
        else if (c < 320) A2[(size_t)r*64 + (c-256)] = f2bf(v);
        else if (c < 336){ A3[(size_t)r*32 + (c-320)] = f2bf(v);
                           A3[(size_t)r*32 + (c-320) + 16] = 0; }
        else if (c < 339) cl[(size_t)r*3 + (c-336)] = v + bc[c-336];
      }
}

// ---------------- fused GEMM + partial logsumexp ----------------
template<int BK>
__global__ __launch_bounds__(512)
void k_gemm_lse(const u16* __restrict__ A, const u16* __restrict__ BT,
                const float* __restrict__ bias, int K, int N,
                MS* __restrict__ P, int ntiles,
                const int* __restrict__ cntp, int bucket)
{
  constexpr int BM = 256, BN = 128;
  if (cntp && (int)(blockIdx.y * BM) >= cntp[bucket]) return;  // compacted M
  __shared__ u16 As[BM * BK];
  __shared__ u16 Bs[BN * BK];
  __shared__ float redm[2][256];
  __shared__ float reds[2][256];

  const int tid  = threadIdx.x;
  const int lane = tid & 63, wid = tid >> 6;
  const int wm = wid & 3, wn = wid >> 2;
  const int l15 = lane & 15, l4 = lane >> 4;
  const int m0 = blockIdx.y * BM;
  const int n0 = blockIdx.x * BN;

  f32x4 acc[4][4];
  #pragma unroll
  for (int m = 0; m < 4; ++m)
    #pragma unroll
    for (int n = 0; n < 4; ++n){ acc[m][n].x=0.f; acc[m][n].y=0.f; acc[m][n].z=0.f; acc[m][n].w=0.f; }

  constexpr int LPR  = BK / 8;
  constexpr int RPC  = 64 / LPR;
  constexpr int ACPW = BM / RPC / 8;
  constexpr int BCPW = BN / RPC / 8;

  const int ksteps = K / BK;
  for (int kt = 0; kt < ksteps; ++kt){
    #pragma unroll
    for (int i = 0; i < ACPW; ++i){
      int c = wid * ACPW + i;
      int row = c * RPC + lane / LPR, kb = lane % LPR;
      glds16((const char*)(A + (size_t)(m0 + row) * K + kt * BK) + kb * 16,
             (char*)As + c * 1024);
    }
    #pragma unroll
    for (int i = 0; i < BCPW; ++i){
      int c = wid * BCPW + i;
      int row = c * RPC + lane / LPR, kb = lane % LPR;
      glds16((const char*)(BT + (size_t)(n0 + row) * K + kt * BK) + kb * 16,
             (char*)Bs + c * 1024);
    }
    __syncthreads();
    #pragma unroll
    for (int ks = 0; ks < BK / 32; ++ks){
      bf16x8 af[4], bfr[4];
      #pragma unroll
      for (int m = 0; m < 4; ++m)
        af[m] = *(const bf16x8*)((const char*)As + (wm*64 + m*16 + l15) * (BK*2) + ks*64 + l4*16);
      #pragma unroll
      for (int n = 0; n < 4; ++n)
        bfr[n] = *(const bf16x8*)((const char*)Bs + (wn*64 + n*16 + l15) * (BK*2) + ks*64 + l4*16);
      #pragma unroll
      for (int m = 0; m < 4; ++m)
        #pragma unroll
        for (int n = 0; n < 4; ++n)
          acc[m][n] = __builtin_amdgcn_mfma_f32_16x16x32_bf16(af[m], bfr[n], acc[m][n], 0, 0, 0);
    }
    __syncthreads();
  }

  float bv[4]; bool val[4];
  #pragma unroll
  for (int n = 0; n < 4; ++n){
    int col = n0 + wn*64 + n*16 + l15;
    val[n] = col < N;
    bv[n] = val[n] ? bias[col] : 0.f;
  }
  #pragma unroll
  for (int m = 0; m < 4; ++m)
    #pragma unroll
    for (int q = 0; q < 4; ++q){
      float mx = -1e30f;
      #pragma unroll
      for (int n = 0; n < 4; ++n)
        if (val[n]) mx = fmaxf(mx, acc[m][n][q] + bv[n]);
      #pragma unroll
      for (int d = 1; d < 16; d <<= 1) mx = fmaxf(mx, __shfl_xor(mx, d));
      if (l15 == 0) redm[wn][wm*64 + m*16 + l4*4 + q] = mx;
    }
  __syncthreads();
  #pragma unroll
  for (int m = 0; m < 4; ++m)
    #pragma unroll
    for (int q = 0; q < 4; ++q){
      int lrow = wm*64 + m*16 + l4*4 + q;
      float M = fmaxf(redm[0][lrow], redm[1][lrow]);
      float s = 0.f;
      #pragma unroll
      for (int n = 0; n < 4; ++n)
        if (val[n]) s += __expf(acc[m][n][q] + bv[n] - M);
      #pragma unroll
      for (int d = 1; d < 16; d <<= 1) s += __shfl_xor(s, d);
      if (l15 == 0) reds[wn][lrow] = s;
    }
  __syncthreads();
  if (wn == 0 && l15 == 0){
    #pragma unroll
    for (int m = 0; m < 4; ++m)
      #pragma unroll
      for (int q = 0; q < 4; ++q){
        int lrow = wm*64 + m*16 + l4*4 + q;
        MS r; r.m = fmaxf(redm[0][lrow], redm[1][lrow]);
        r.s = reds[0][lrow] + reds[1][lrow];
        P[(size_t)(m0 + lrow) * ntiles + blockIdx.x] = r;
      }
  }
}

// ---------------- target logit for tokens in [start,end) ----------------
__global__ void k_target(const int* __restrict__ tgt, const u16* __restrict__ A,
                         const u16* __restrict__ BT, const float* __restrict__ bias,
                         int start, int end, int K, float* __restrict__ tl)
{
  int n = blockIdx.x * 4 + (threadIdx.x >> 6);
  int lane = threadIdx.x & 63;
  int t = tgt[n];
  if (t < start || t >= end) return;
  int rel = t - start;
  const u16* a = A  + (size_t)n   * K;
  const u16* b = BT + (size_t)rel * K;
  float s = 0.f;
  for (int k = lane * 8; k < K; k += 512){
    u16x8 av = *(const u16x8*)(a + k);
    u16x8 bv = *(const u16x8*)(b + k);
    #pragma unroll
    for (int j = 0; j < 8; ++j) s += bf2f(av[j]) * bf2f(bv[j]);
  }
  #pragma unroll
  for (int d = 1; d < 64; d <<= 1) s += __shfl_xor(s, d);
  if (lane == 0) tl[n] = s + bias[rel];
}

// ---------------- final combine ----------------
__device__ __forceinline__ void lse_merge(float& m, float& s, float m2, float s2){
  float M = fmaxf(m, m2);
  s = s * __expf(m - M) + s2 * __expf(m2 - M);
  m = M;
}

__global__ void k_finalize(const int* __restrict__ tgt, const MS* __restrict__ P,
                           const float* __restrict__ cl, const float* __restrict__ tl,
                           const int* __restrict__ pos, float* __restrict__ out)
{
  const int NT0 = 157, NT1 = 313, NT2 = 938, NT3 = 686;
  int n = blockIdx.x * 4 + (threadIdx.x >> 6);
  int lane = threadIdx.x & 63;
  int t = tgt[n];

  float m = -1e30f, s = 0.f;
  const MS* p0 = P + (size_t)n * NT0;
  for (int i = lane; i < NT0; i += 64){ MS v = p0[i]; lse_merge(m, s, v.m, v.s); }
  if (lane < 3) lse_merge(m, s, cl[n*3 + lane], 1.f);
  #pragma unroll
  for (int d = 1; d < 64; d <<= 1){
    float m2 = __shfl_xor(m, d), s2 = __shfl_xor(s, d);
    lse_merge(m, s, m2, s2);
  }
  float lse_head = m + logf(s);

  float nll;
  if (t < 20000){
    nll = lse_head - tl[n];
  } else {
    int seg, nt; size_t base;
    if      (t <  60000){ seg = 1; nt = NT1; base = (size_t)1024 * NT0; }
    else if (t < 180000){ seg = 2; nt = NT2; base = (size_t)1024 * (NT0 + NT1); }
    else                { seg = 3; nt = NT3; base = (size_t)1024 * (NT0 + NT1 + NT2); }
    float m2 = -1e30f, s2 = 0.f;
    const MS* ps = P + base + (size_t)pos[n] * nt;
    for (int i = lane; i < nt; i += 64){ MS v = ps[i]; lse_merge(m2, s2, v.m, v.s); }
    #pragma unroll
    for (int d = 1; d < 64; d <<= 1){
      float mm = __shfl_xor(m2, d), ss = __shfl_xor(s2, d);
      lse_merge(m2, s2, mm, ss);
    }
    float lse_t = m2 + logf(s2);
    nll = lse_head - cl[n*3 + (3 - seg)] + lse_t - tl[n];
  }
  if (lane == 0) out[n] = nll;
}

// ---------------------------------------------------------------------------
extern "C" void kernel_launch(void* const* d_in, const int* in_sizes, int n_in,
                              void* d_out, int out_size, void* d_ws, size_t ws_size,
                              hipStream_t stream)
{
  const float* hidden = (const float*)d_in[0];
  const int*   target = (const int*)d_in[1];
  const float* W_head = (const float*)d_in[2];
  const float* b_head = (const float*)d_in[3];
  const float* W_clu  = (const float*)d_in[4];
  const float* b_clu  = (const float*)d_in[5];
  const float* W_p1   = (const float*)d_in[6];
  const float* W_t1   = (const float*)d_in[7];
  const float* b_t1   = (const float*)d_in[8];
  const float* W_p2   = (const float*)d_in[9];
  const float* W_t2   = (const float*)d_in[10];
  const float* b_t2   = (const float*)d_in[11];
  const float* W_p3   = (const float*)d_in[12];
  const float* W_t3   = (const float*)d_in[13];
  const float* b_t3   = (const float*)d_in[14];
  float* out = (float*)d_out;

  // workspace layout (bytes; max footprint ~61.9 MB)
  char* ws = (char*)d_ws;
  u16*   A0  = (u16*)(ws + 0);          // [1024][1024] bf16
  u16*   A1  = (u16*)(ws + 2097152);    // [1024][256]
  u16*   A2  = (u16*)(ws + 2621440);    // [1024][64]
  u16*   A3  = (u16*)(ws + 2752512);    // [1024][32]
  float* cl  = (float*)(ws + 2818048);  // [1024][3]
  float* tl  = (float*)(ws + 2834432);  // [1024]
  MS*    P   = (MS*)(ws + 2838528);     // [1024][157+313+938+686] (16.4 MB)
  u16*   BTp = (u16*)(ws + 2838528);    // proj weights [400][1024] bf16; dead
                                        // before head GEMM writes P (overlap ok)
  u16*   BT  = (u16*)(ws + 19992576);   // reusable transposed-W (41.2 MB)
  int*   cnt  = (int*)(ws + 61149184);  // [4]
  int*   idx1 = (int*)(ws + 61149440);
  int*   idx2 = (int*)(ws + 61153536);
  int*   idx3 = (int*)(ws + 61157632);
  int*   pos  = (int*)(ws + 61161728);
  u16*   A1c  = (u16*)(ws + 61165824);  // [1024][256]
  u16*   A2c  = (u16*)(ws + 61690112);  // [1024][64]
  u16*   A3c  = (u16*)(ws + 61821184);  // [1024][32]

  const size_t P1 = (size_t)1024 * 157;
  const size_t P2 = (size_t)1024 * (157 + 313);
  const size_t P3 = (size_t)1024 * (157 + 313 + 938);

  k_cvt_hidden<<<512, 256, 0, stream>>>(hidden, A0, cnt);
  k_compact<<<4, 256, 0, stream>>>(target, cnt, idx1, idx2, idx3, pos);

  // proj weights -> BTp rows: [0,256)=Wp1^T, [256,320)=Wp2^T, [320,336)=Wp3^T
  // (transpose zero-fills to row 383), [336,339)=Wc^T (zero-fills to 399).
  k_transpose<<<dim3(4, 16), 256, 0, stream>>>(W_p1, 1024, 256, BTp, 1024);
  k_transpose<<<dim3(1, 16), 256, 0, stream>>>(W_p2, 1024, 64, BTp + (size_t)256*1024, 1024);
  k_transpose<<<dim3(1, 16), 256, 0, stream>>>(W_p3, 1024, 16, BTp + (size_t)320*1024, 1024);
  k_transpose<<<dim3(1, 16), 256, 0, stream>>>(W_clu, 1024, 3, BTp + (size_t)336*1024, 1024);
  k_proj_gemm<<<dim3(3, 4), 512, 0, stream>>>(A0, BTp, b_clu, A1, A2, A3, cl);
  k_gather<<<176, 256, 0, stream>>>(cnt, idx1, idx2, idx3, A1, A2, A3, A1c, A2c, A3c);

  // seg0: head (K=1024, N=20000, 157 tiles, all 1024 rows)
  k_transpose<<<dim3(314, 16), 256, 0, stream>>>(W_head, 1024, 20000, BT, 1024);
  k_gemm_lse<64><<<dim3(157, 4), 512, 0, stream>>>(A0, BT, b_head, 1024, 20000, P, 157, nullptr, 0);
  k_target<<<256, 256, 0, stream>>>(target, A0, BT, b_head, 0, 20000, 1024, tl);

  // seg1: tail1 (K=256, N=40000, 313 tiles, compacted rows)
  k_transpose<<<dim3(626, 4), 256, 0, stream>>>(W_t1, 256, 40000, BT, 256);
  k_gemm_lse<64><<<dim3(313, 4), 512, 0, stream>>>(A1c, BT, b_t1, 256, 40000, P + P1, 313, cnt, 0);
  k_target<<<256, 256, 0, stream>>>(target, A1, BT, b_t1, 20000, 60000, 256, tl);

  // seg2: tail2 (K=64, N=120000, 938 tiles, compacted rows)
  k_transpose<<<dim3(1876, 1), 256, 0, stream>>>(W_t2, 64, 120000, BT, 64);
  k_gemm_lse<64><<<dim3(938, 4), 512, 0, stream>>>(A2c, BT, b_t2, 64, 120000, P + P2, 938, cnt, 1);
  k_target<<<256, 256, 0, stream>>>(target, A2, BT, b_t2, 60000, 180000, 64, tl);

  // seg3: tail3 (K=16 padded to 32, N=87735, 686 tiles, compacted rows)
  k_transpose<<<dim3(1372, 1), 256, 0, stream>>>(W_t3, 16, 87735, BT, 32);
  k_gemm_lse<32><<<dim3(686, 4), 512, 0, stream>>>(A3c, BT, b_t3, 32, 87735, P + P3, 686, cnt, 2);
  k_target<<<256, 256, 0, stream>>>(target, A3, BT, b_t3, 180000, 267735, 32, tl);

  k_finalize<<<256, 256, 0, stream>>>(target, P, cl, tl, pos, out);
}

// Round 3
// 312.846 us; speedup vs baseline: 1.4518x; 1.0489x over previous
//
#include <hip/hip_runtime.h>
#include <cstdint>
#include <cstddef>

// ---------------------------------------------------------------------------
// Adaptive log-softmax NLL. bf16 MFMA GEMMs fused with online logsumexp.
// R3: gemm_lse -> m97-exact 128x128x64 4-wave structure + T2 swizzle
// (pre-swizzled glds source, swizzled ds_read); target-logit extraction fused
// into GEMM epilogue (k_target gone); multi-job transpose kernel (few
// launches); runtime ws_size branch: separate per-segment BT if ws allows.
// ---------------------------------------------------------------------------

typedef unsigned short u16;
typedef __attribute__((ext_vector_type(8))) __bf16 bf16x8;
typedef __attribute__((ext_vector_type(8))) u16 u16x8;
typedef __attribute__((ext_vector_type(4))) float f32x4;

#define AS1 __attribute__((address_space(1)))
#define AS3 __attribute__((address_space(3)))

struct MS { float m, s; };

__device__ __forceinline__ u16 f2bf(float f){
  union { float f; unsigned u; } v; v.f = f;
  unsigned r = v.u + 0x7fffu + ((v.u >> 16) & 1u);  // RNE
  return (u16)(r >> 16);
}
__device__ __forceinline__ float bf2f(u16 x){
  union { unsigned u; float f; } v; v.u = ((unsigned)x) << 16;
  return v.f;
}
__device__ __forceinline__ void glds16(const void* g, void* l){
  __builtin_amdgcn_global_load_lds((AS1 unsigned*)(uintptr_t)g,
                                   (AS3 unsigned*)(unsigned)(uintptr_t)l, 16, 0, 0);
}

// ---------------- hidden f32 -> bf16 (+ init cnt and tgt_rel) ----------------
__global__ void k_cvt_hidden(const float* __restrict__ h, u16* __restrict__ a0,
                             int* __restrict__ cnt, int* __restrict__ trel){
  int g = blockIdx.x * 256 + threadIdx.x;
  if (g < 4096) trel[g] = -1;          // tr0..tr3, 1024 each, contiguous
  if (g < 4) cnt[g] = 0;
  int i = g * 8;
  f32x4 v0 = *(const f32x4*)(h + i);
  f32x4 v1 = *(const f32x4*)(h + i + 4);
  u16x8 o;
  o[0]=f2bf(v0.x); o[1]=f2bf(v0.y); o[2]=f2bf(v0.z); o[3]=f2bf(v0.w);
  o[4]=f2bf(v1.x); o[5]=f2bf(v1.y); o[6]=f2bf(v1.z); o[7]=f2bf(v1.w);
  *(u16x8*)(a0 + i) = o;
}

// ---------------- bucket compaction ----------------
// Order within a bucket is atomic-nondeterministic; harmless: per-row values
// are position-independent and results scatter back via pos[n]/idx[p].
__global__ void k_compact(const int* __restrict__ tgt, int* __restrict__ cnt,
                          int* __restrict__ idx1, int* __restrict__ idx2,
                          int* __restrict__ idx3, int* __restrict__ pos,
                          int* __restrict__ tr0, int* __restrict__ tr1,
                          int* __restrict__ tr2, int* __restrict__ tr3){
  int n = blockIdx.x * 256 + threadIdx.x;
  int t = tgt[n];
  int p = 0;
  tr0[n] = (t < 20000) ? t : -1;
  if (t >= 20000){
    int b = (t < 60000) ? 0 : (t < 180000 ? 1 : 2);
    p = atomicAdd(&cnt[b], 1);
    if (b == 0){ idx1[p] = n; tr1[p] = t - 20000; }
    else if (b == 1){ idx2[p] = n; tr2[p] = t - 60000; }
    else { idx3[p] = n; tr3[p] = t - 180000; }
  }
  pos[n] = p;
}

// ---------------- gather compacted tail-A rows ----------------
__global__ void k_gather(const int* __restrict__ cnt,
                         const int* __restrict__ idx1, const int* __restrict__ idx2,
                         const int* __restrict__ idx3,
                         const u16* __restrict__ A1, const u16* __restrict__ A2,
                         const u16* __restrict__ A3,
                         u16* __restrict__ A1c, u16* __restrict__ A2c,
                         u16* __restrict__ A3c){
  int u = blockIdx.x * 256 + threadIdx.x;
  const u16* src; u16* dst;
  if (u < 32768){                       // A1: 1024 rows x 32 chunks(8 elem)
    int r = u >> 5, c = u & 31;
    if (r >= cnt[0]) return;
    src = A1 + (size_t)idx1[r] * 256 + c * 8;
    dst = A1c + (size_t)r * 256 + c * 8;
  } else if (u < 40960){                // A2: 1024 x 8
    int v = u - 32768; int r = v >> 3, c = v & 7;
    if (r >= cnt[1]) return;
    src = A2 + (size_t)idx2[r] * 64 + c * 8;
    dst = A2c + (size_t)r * 64 + c * 8;
  } else {                              // A3: 1024 x 4
    int v = u - 40960; int r = v >> 2, c = v & 3;
    if (r >= cnt[2]) return;
    src = A3 + (size_t)idx3[r] * 32 + c * 8;
    dst = A3c + (size_t)r * 32 + c * 8;
  }
  *(u16x8*)dst = *(const u16x8*)src;
}

// ---------------- multi-job W [K][N] f32 -> BT [nrows][Kpad] bf16 ----------
struct TJob { const float* W; u16* BT; int K, N, Kpad, nrows, nx, base; };
struct TJobs { TJob j[8]; int nj; };

__global__ void k_transpose_multi(TJobs jobs){
  int id = blockIdx.x;
  int ji = 0;
  #pragma unroll
  for (int i = 1; i < 8; ++i)
    if (i < jobs.nj && id >= jobs.j[i].base) ji = i;
  TJob jb = jobs.j[ji];
  int local = id - jb.base;
  int bx = local % jb.nx;
  int by = local / jb.nx;

  __shared__ float t[64][65];
  const int n0 = bx * 64;
  const int k0 = by * 64;
  const bool al = (jb.N & 3) == 0;
  for (int i = threadIdx.x; i < 64*16; i += 256){
    int r = i >> 4, c4 = (i & 15) * 4;
    int k = k0 + r, n = n0 + c4;
    f32x4 v; v.x=0.f; v.y=0.f; v.z=0.f; v.w=0.f;
    if (k < jb.K){
      if (al && n + 3 < jb.N) v = *(const f32x4*)(jb.W + (size_t)k * jb.N + n);
      else { for (int q = 0; q < 4; ++q) if (n + q < jb.N) v[q] = jb.W[(size_t)k * jb.N + n + q]; }
    }
    t[r][c4] = v.x; t[r][c4+1] = v.y; t[r][c4+2] = v.z; t[r][c4+3] = v.w;
  }
  __syncthreads();
  for (int i = threadIdx.x; i < 64*8; i += 256){
    int rn = i >> 3, c8 = (i & 7) * 8;
    if (k0 + c8 < jb.Kpad && (n0 + rn) < jb.nrows){
      u16x8 o;
      #pragma unroll
      for (int q = 0; q < 8; ++q) o[q] = f2bf(t[c8 + q][rn]);
      *(u16x8*)(jb.BT + (size_t)(n0 + rn) * jb.Kpad + k0 + c8) = o;
    }
  }
}

// ---------------- projection GEMM: A0[1024][1024] x BTp[384][1024]^T -------
__global__ __launch_bounds__(512)
void k_proj_gemm(const u16* __restrict__ A, const u16* __restrict__ BT,
                 const float* __restrict__ bc,
                 u16* __restrict__ A1, u16* __restrict__ A2,
                 u16* __restrict__ A3, float* __restrict__ cl)
{
  constexpr int BK = 64, K = 1024;
  __shared__ u16 As[256 * BK];
  __shared__ u16 Bs[128 * BK];
  const int tid  = threadIdx.x;
  const int lane = tid & 63, wid = tid >> 6;
  const int wm = wid & 3, wn = wid >> 2;
  const int l15 = lane & 15, l4 = lane >> 4;
  const int m0 = blockIdx.y * 256;
  const int n0 = blockIdx.x * 128;

  f32x4 acc[4][4];
  #pragma unroll
  for (int m = 0; m < 4; ++m)
    #pragma unroll
    for (int n = 0; n < 4; ++n){ acc[m][n].x=0.f; acc[m][n].y=0.f; acc[m][n].z=0.f; acc[m][n].w=0.f; }

  for (int kt = 0; kt < K / BK; ++kt){
    #pragma unroll
    for (int i = 0; i < 4; ++i){
      int c = wid * 4 + i;
      int row = c * 8 + lane / 8, kb = lane % 8;
      glds16((const char*)(A + (size_t)(m0 + row) * K + kt * BK) + kb * 16,
             (char*)As + c * 1024);
    }
    #pragma unroll
    for (int i = 0; i < 2; ++i){
      int c = wid * 2 + i;
      int row = c * 8 + lane / 8, kb = lane % 8;
      glds16((const char*)(BT + (size_t)(n0 + row) * K + kt * BK) + kb * 16,
             (char*)Bs + c * 1024);
    }
    __syncthreads();
    #pragma unroll
    for (int ks = 0; ks < 2; ++ks){
      bf16x8 af[4], bfr[4];
      #pragma unroll
      for (int m = 0; m < 4; ++m)
        af[m] = *(const bf16x8*)((const char*)As + (wm*64 + m*16 + l15) * (BK*2) + ks*64 + l4*16);
      #pragma unroll
      for (int n = 0; n < 4; ++n)
        bfr[n] = *(const bf16x8*)((const char*)Bs + (wn*64 + n*16 + l15) * (BK*2) + ks*64 + l4*16);
      #pragma unroll
      for (int m = 0; m < 4; ++m)
        #pragma unroll
        for (int n = 0; n < 4; ++n)
          acc[m][n] = __builtin_amdgcn_mfma_f32_16x16x32_bf16(af[m], bfr[n], acc[m][n], 0, 0, 0);
    }
    __syncthreads();
  }
  #pragma unroll
  for (int m = 0; m < 4; ++m)
    #pragma unroll
    for (int n = 0; n < 4; ++n)
      #pragma unroll
      for (int q = 0; q < 4; ++q){
        int c = n0 + wn*64 + n*16 + l15;
        int r = m0 + wm*64 + m*16 + l4*4 + q;
        float v = acc[m][n][q];
        if (c < 256)      A1[(size_t)r*256 + c] = f2bf(v);
        else if (c < 320) A2[(size_t)r*64 + (c-256)] = f2bf(v);
        else if (c < 336){ A3[(size_t)r*32 + (c-320)] = f2bf(v);
                           A3[(size_t)r*32 + (c-320) + 16] = 0; }
        else if (c < 339) cl[(size_t)r*3 + (c-336)] = v + bc[c-336];
      }
}

// ---------------- fused GEMM + partial logsumexp + target extraction -------
// m97-exact geometry: BM=BN=128, BK=64(or 32), 4 waves, single-buffer,
// 2-barrier loop; T2 swizzle: linear glds dest, XOR'd global source chunk,
// XOR'd ds_read chunk (rule #21: source perm == read perm).
template<int BK>
__global__ __launch_bounds__(256)
void k_gemm_lse(const u16* __restrict__ A, const u16* __restrict__ BT,
                const float* __restrict__ bias, int K, int N,
                MS* __restrict__ P, int ntiles,
                const int* __restrict__ cntp, int bucket,
                const int* __restrict__ tgt_rel, const int* __restrict__ rowmap,
                float* __restrict__ tl)
{
  constexpr int BM = 128, BN = 128;
  constexpr int CH  = BK / 8;          // 16B chunks per LDS row
  constexpr int LPR = CH;              // staging lanes per row
  constexpr int RPC = 64 / LPR;        // rows per 1KB chunk
  constexpr int NC  = BM * BK * 2 / 1024;  // 1KB chunks per matrix
  constexpr int CPW = NC / 4;          // chunks per wave
  if (cntp && (int)(blockIdx.y * BM) >= cntp[bucket]) return;
  __shared__ u16 As[BM * BK];
  __shared__ u16 Bs[BN * BK];
  __shared__ float redm[2][BM];
  __shared__ float reds[2][BM];

  const int tid  = threadIdx.x;
  const int lane = tid & 63, wid = tid >> 6;
  const int wm = wid & 1, wn = wid >> 1;
  const int l15 = lane & 15, l4 = lane >> 4;
  const int m0 = blockIdx.y * BM;
  const int n0 = blockIdx.x * BN;
  const int srow = lane / LPR;         // staging row within chunk
  const int skb  = lane % LPR;         // staging 16B slot

  f32x4 acc[4][4];
  #pragma unroll
  for (int m = 0; m < 4; ++m)
    #pragma unroll
    for (int n = 0; n < 4; ++n){ acc[m][n].x=0.f; acc[m][n].y=0.f; acc[m][n].z=0.f; acc[m][n].w=0.f; }

  const int ksteps = K / BK;
  for (int kt = 0; kt < ksteps; ++kt){
    #pragma unroll
    for (int i = 0; i < CPW; ++i){
      int c = wid * CPW + i;
      int row = c * RPC + srow;
      int kbs = skb ^ (row & (CH - 1));   // pre-swizzled source chunk
      glds16((const char*)(A + (size_t)(m0 + row) * K + kt * BK) + kbs * 16,
             (char*)As + c * 1024);
    }
    #pragma unroll
    for (int i = 0; i < CPW; ++i){
      int c = wid * CPW + i;
      int row = c * RPC + srow;
      int kbs = skb ^ (row & (CH - 1));
      glds16((const char*)(BT + (size_t)(n0 + row) * K + kt * BK) + kbs * 16,
             (char*)Bs + c * 1024);
    }
    __syncthreads();
    #pragma unroll
    for (int ks = 0; ks < BK / 32; ++ks){
      bf16x8 af[4], bfr[4];
      #pragma unroll
      for (int m = 0; m < 4; ++m){
        int r = wm*64 + m*16 + l15;
        af[m] = *(const bf16x8*)((const char*)As + r*(BK*2) + (((ks*4 + l4) ^ (r & (CH-1))) * 16));
      }
      #pragma unroll
      for (int n = 0; n < 4; ++n){
        int r = wn*64 + n*16 + l15;
        bfr[n] = *(const bf16x8*)((const char*)Bs + r*(BK*2) + (((ks*4 + l4) ^ (r & (CH-1))) * 16));
      }
      #pragma unroll
      for (int m = 0; m < 4; ++m)
        #pragma unroll
        for (int n = 0; n < 4; ++n)
          acc[m][n] = __builtin_amdgcn_mfma_f32_16x16x32_bf16(af[m], bfr[n], acc[m][n], 0, 0, 0);
    }
    __syncthreads();
  }

  // ---- epilogue ----
  float bv[4]; bool val[4];
  #pragma unroll
  for (int n = 0; n < 4; ++n){
    int col = n0 + wn*64 + n*16 + l15;
    val[n] = col < N;
    bv[n] = val[n] ? bias[col] : 0.f;
  }
  // target-logit extraction: this block holds logit (row, tgt_rel[row]) iff
  // tgt_rel[row] falls in [n0, n0+BN). Unique writer across the grid.
  #pragma unroll
  for (int m = 0; m < 4; ++m)
    #pragma unroll
    for (int q = 0; q < 4; ++q){
      int row = m0 + wm*64 + m*16 + l4*4 + q;
      int tr = tgt_rel[row];
      if (tr >= 0){
        #pragma unroll
        for (int n = 0; n < 4; ++n){
          int col = n0 + wn*64 + n*16 + l15;
          if (tr == col)
            tl[rowmap ? rowmap[row] : row] = acc[m][n][q] + bv[n];
        }
      }
    }
  // per-row max over this 128-col tile
  #pragma unroll
  for (int m = 0; m < 4; ++m)
    #pragma unroll
    for (int q = 0; q < 4; ++q){
      float mx = -1e30f;
      #pragma unroll
      for (int n = 0; n < 4; ++n)
        if (val[n]) mx = fmaxf(mx, acc[m][n][q] + bv[n]);
      #pragma unroll
      for (int d = 1; d < 16; d <<= 1) mx = fmaxf(mx, __shfl_xor(mx, d));
      if (l15 == 0) redm[wn][wm*64 + m*16 + l4*4 + q] = mx;
    }
  __syncthreads();
  #pragma unroll
  for (int m = 0; m < 4; ++m)
    #pragma unroll
    for (int q = 0; q < 4; ++q){
      int lrow = wm*64 + m*16 + l4*4 + q;
      float M = fmaxf(redm[0][lrow], redm[1][lrow]);
      float s = 0.f;
      #pragma unroll
      for (int n = 0; n < 4; ++n)
        if (val[n]) s += __expf(acc[m][n][q] + bv[n] - M);
      #pragma unroll
      for (int d = 1; d < 16; d <<= 1) s += __shfl_xor(s, d);
      if (l15 == 0) reds[wn][lrow] = s;
    }
  __syncthreads();
  if (wn == 0 && l15 == 0){
    #pragma unroll
    for (int m = 0; m < 4; ++m)
      #pragma unroll
      for (int q = 0; q < 4; ++q){
        int lrow = wm*64 + m*16 + l4*4 + q;
        MS r; r.m = fmaxf(redm[0][lrow], redm[1][lrow]);
        r.s = reds[0][lrow] + reds[1][lrow];
        P[(size_t)(m0 + lrow) * ntiles + blockIdx.x] = r;
      }
  }
}

// ---------------- final combine ----------------
__device__ __forceinline__ void lse_merge(float& m, float& s, float m2, float s2){
  float M = fmaxf(m, m2);
  s = s * __expf(m - M) + s2 * __expf(m2 - M);
  m = M;
}

__global__ void k_finalize(const int* __restrict__ tgt, const MS* __restrict__ P,
                           const float* __restrict__ cl, const float* __restrict__ tl,
                           const int* __restrict__ pos, float* __restrict__ out)
{
  const int NT0 = 157, NT1 = 313, NT2 = 938, NT3 = 686;
  int n = blockIdx.x * 4 + (threadIdx.x >> 6);
  int lane = threadIdx.x & 63;
  int t = tgt[n];

  float m = -1e30f, s = 0.f;
  const MS* p0 = P + (size_t)n * NT0;
  for (int i = lane; i < NT0; i += 64){ MS v = p0[i]; lse_merge(m, s, v.m, v.s); }
  if (lane < 3) lse_merge(m, s, cl[n*3 + lane], 1.f);
  #pragma unroll
  for (int d = 1; d < 64; d <<= 1){
    float m2 = __shfl_xor(m, d), s2 = __shfl_xor(s, d);
    lse_merge(m, s, m2, s2);
  }
  float lse_head = m + logf(s);

  float nll;
  if (t < 20000){
    nll = lse_head - tl[n];
  } else {
    int seg, nt; size_t base;
    if      (t <  60000){ seg = 1; nt = NT1; base = (size_t)1024 * NT0; }
    else if (t < 180000){ seg = 2; nt = NT2; base = (size_t)1024 * (NT0 + NT1); }
    else                { seg = 3; nt = NT3; base = (size_t)1024 * (NT0 + NT1 + NT2); }
    float m2 = -1e30f, s2 = 0.f;
    const MS* ps = P + base + (size_t)pos[n] * nt;
    for (int i = lane; i < nt; i += 64){ MS v = ps[i]; lse_merge(m2, s2, v.m, v.s); }
    #pragma unroll
    for (int d = 1; d < 64; d <<= 1){
      float mm = __shfl_xor(m2, d), ss = __shfl_xor(s2, d);
      lse_merge(m2, s2, mm, ss);
    }
    float lse_t = m2 + logf(s2);
    // reference quirk: bucket i uses head_lp[:, -i] == cluster logit index 3-i
    nll = lse_head - cl[n*3 + (3 - seg)] + lse_t - tl[n];
  }
  if (lane == 0) out[n] = nll;
}

// ---------------------------------------------------------------------------
extern "C" void kernel_launch(void* const* d_in, const int* in_sizes, int n_in,
                              void* d_out, int out_size, void* d_ws, size_t ws_size,
                              hipStream_t stream)
{
  const float* hidden = (const float*)d_in[0];
  const int*   target = (const int*)d_in[1];
  const float* W_head = (const float*)d_in[2];
  const float* b_head = (const float*)d_in[3];
  const float* W_clu  = (const float*)d_in[4];
  const float* b_clu  = (const float*)d_in[5];
  const float* W_p1   = (const float*)d_in[6];
  const float* W_t1   = (const float*)d_in[7];
  const float* b_t1   = (const float*)d_in[8];
  const float* W_p2   = (const float*)d_in[9];
  const float* W_t2   = (const float*)d_in[10];
  const float* b_t2   = (const float*)d_in[11];
  const float* W_p3   = (const float*)d_in[12];
  const float* W_t3   = (const float*)d_in[13];
  const float* b_t3   = (const float*)d_in[14];
  float* out = (float*)d_out;

  // workspace layout (bytes)
  char* ws = (char*)d_ws;
  u16*   A0  = (u16*)(ws + 0);          // [1024][1024] bf16
  u16*   A1  = (u16*)(ws + 2097152);    // [1024][256]
  u16*   A2  = (u16*)(ws + 2621440);    // [1024][64]
  u16*   A3  = (u16*)(ws + 2752512);    // [1024][32]
  float* cl  = (float*)(ws + 2818048);  // [1024][3]
  float* tl  = (float*)(ws + 2834432);  // [1024]
  MS*    P   = (MS*)(ws + 2838528);     // [1024][2094] (17.2 MB)
  u16*   BTp = (u16*)(ws + 2838528);    // proj weights [400][1024]; dead
                                        // before head GEMM writes P
  u16*   BTh = (u16*)(ws + 19992576);   // head BT [20096][1024] (41.2 MB)
  int*   cnt  = (int*)(ws + 61149184);  // [4]
  int*   idx1 = (int*)(ws + 61149440);
  int*   idx2 = (int*)(ws + 61153536);
  int*   idx3 = (int*)(ws + 61157632);
  int*   pos  = (int*)(ws + 61161728);
  u16*   A1c  = (u16*)(ws + 61165824);  // [1024][256]
  u16*   A2c  = (u16*)(ws + 61690112);  // [1024][64]
  u16*   A3c  = (u16*)(ws + 61821184);  // [1024][32]
  int*   tr0  = (int*)(ws + 61886720);  // [1024] x4, contiguous
  int*   tr1  = (int*)(ws + 61890816);
  int*   tr2  = (int*)(ws + 61894912);
  int*   tr3  = (int*)(ws + 61899008);
  // path A (big ws): dedicated tail BT regions
  u16*   BT1  = (u16*)(ws + 61903104);  // [40064][256]  (20.5 MB)
  u16*   BT2  = (u16*)(ws + 82415872);  // [120064][64]  (15.4 MB)
  u16*   BT3  = (u16*)(ws + 97784064);  // [87808][32]   ( 5.6 MB)
  const size_t needA = 103403776;
  const bool bigws = ws_size >= needA;

  const size_t P1 = (size_t)1024 * 157;
  const size_t P2 = (size_t)1024 * (157 + 313);
  const size_t P3 = (size_t)1024 * (157 + 313 + 938);

  k_cvt_hidden<<<512, 256, 0, stream>>>(hidden, A0, cnt, tr0);
  k_compact<<<4, 256, 0, stream>>>(target, cnt, idx1, idx2, idx3, pos,
                                   tr0, tr1, tr2, tr3);

  // ---- transposes ----
  TJobs tj{}; int nb = 0;
  auto add = [&](const float* W, u16* B, int K, int N, int Kpad, int nrows){
    int nx = (nrows + 63) / 64;
    int ny = (Kpad + 63) / 64;
    tj.j[tj.nj++] = TJob{W, B, K, N, Kpad, nrows, nx, nb};
    nb += nx * ny;
  };
  // proj weights + head (BTp overlays P region; written before P is live)
  add(W_p1, BTp, 1024, 256, 1024, 256);
  add(W_p2, BTp + (size_t)256*1024, 1024, 64, 1024, 64);
  add(W_p3, BTp + (size_t)320*1024, 1024, 16, 1024, 16);
  add(W_clu, BTp + (size_t)336*1024, 1024, 3, 1024, 64);
  add(W_head, BTh, 1024, 20000, 1024, 20096);
  if (bigws){
    add(W_t1, BT1, 256, 40000, 256, 40064);
    add(W_t2, BT2, 64, 120000, 64, 120064);
    add(W_t3, BT3, 16, 87735, 32, 87808);
  }
  k_transpose_multi<<<nb, 256, 0, stream>>>(tj);

  k_proj_gemm<<<dim3(3, 4), 512, 0, stream>>>(A0, BTp, b_clu, A1, A2, A3, cl);
  k_gather<<<176, 256, 0, stream>>>(cnt, idx1, idx2, idx3, A1, A2, A3, A1c, A2c, A3c);

  // ---- GEMM+LSE per segment ----
  k_gemm_lse<64><<<dim3(157, 8), 256, 0, stream>>>(A0, BTh, b_head, 1024, 20000,
      P, 157, nullptr, 0, tr0, nullptr, tl);

  if (bigws){
    k_gemm_lse<64><<<dim3(313, 8), 256, 0, stream>>>(A1c, BT1, b_t1, 256, 40000,
        P + P1, 313, cnt, 0, tr1, idx1, tl);
    k_gemm_lse<64><<<dim3(938, 8), 256, 0, stream>>>(A2c, BT2, b_t2, 64, 120000,
        P + P2, 938, cnt, 1, tr2, idx2, tl);
    k_gemm_lse<32><<<dim3(686, 8), 256, 0, stream>>>(A3c, BT3, b_t3, 32, 87735,
        P + P3, 686, cnt, 2, tr3, idx3, tl);
  } else {
    // small ws: tails sequentially reuse BTh region
    TJobs s1{}; s1.nj = 1; s1.j[0] = TJob{W_t1, BTh, 256, 40000, 256, 40064, 626, 0};
    k_transpose_multi<<<626*4, 256, 0, stream>>>(s1);
    k_gemm_lse<64><<<dim3(313, 8), 256, 0, stream>>>(A1c, BTh, b_t1, 256, 40000,
        P + P1, 313, cnt, 0, tr1, idx1, tl);
    TJobs s2{}; s2.nj = 1; s2.j[0] = TJob{W_t2, BTh, 64, 120000, 64, 120064, 1876, 0};
    k_transpose_multi<<<1876, 256, 0, stream>>>(s2);
    k_gemm_lse<64><<<dim3(938, 8), 256, 0, stream>>>(A2c, BTh, b_t2, 64, 120000,
        P + P2, 938, cnt, 1, tr2, idx2, tl);
    TJobs s3{}; s3.nj = 1; s3.j[0] = TJob{W_t3, BTh, 16, 87735, 32, 87808, 1372, 0};
    k_transpose_multi<<<1372, 256, 0, stream>>>(s3);
    k_gemm_lse<32><<<dim3(686, 8), 256, 0, stream>>>(A3c, BTh, b_t3, 32, 87735,
        P + P3, 686, cnt, 2, tr3, idx3, tl);
  }

  k_finalize<<<256, 256, 0, stream>>>(target, P, cl, tl, pos, out);
}